// Round 4
// baseline (13561.438 us; speedup 1.0000x reference)
//
#include <hip/hip_runtime.h>

#define B_ 128
#define T_ 512
#define I_ 64
#define R_ 512
#define O_ 64
#define NG 8          // batch groups (16 batches each)
#define GB 16

typedef _Float16 f16;
typedef __attribute__((ext_vector_type(8))) _Float16 half8;
typedef __attribute__((ext_vector_type(4))) float f32x4;

#define MFMA16 __builtin_amdgcn_mfma_f32_16x16x32_f16

// RNN block: 1024 threads = 16 waves, TWO independent batch-groups per block
// (4 blocks total). Wave w: group q=w>>3, rows [64*(w&7), 64*(w&7)+64).
// All 64 W A-frags live in registers (256 arch VGPR+AGPR, 512-class at 4
// waves/SIMD) -> zero per-step A-frag LDS reads; W is shared by both groups.
// The two groups' waves have independent dep chains, so each SIMD's 4 waves
// overlap one group's tanh/publish tail with the other's MFMA stream,
// amortizing the fixed per-step cost (barrier + drain + LDS read ramp).
#define HBYTES 16384
#define GSTRIDE (2 * HBYTES)                   // per-group LDS (2 parities)
#define SMEM_TOTAL (2 * GSTRIDE)               // 65536

__device__ __forceinline__ float tanh_fast(float x) {
    float e = __expf(2.0f * x);
    return 1.0f - 2.0f * __builtin_amdgcn_rcpf(e + 1.0f);
}

__device__ __forceinline__ half8 cvt_h8(const float4 a, const float4 b) {
    half8 r;
    r[0] = (f16)a.x; r[1] = (f16)a.y; r[2] = (f16)a.z; r[3] = (f16)a.w;
    r[4] = (f16)b.x; r[5] = (f16)b.y; r[6] = (f16)b.z; r[7] = (f16)b.w;
    return r;
}

__device__ __forceinline__ unsigned pack2(float a, float b) {
    union { f16 h[2]; unsigned u; } r;
    r.h[0] = (f16)a; r.h[1] = (f16)b; return r.u;
}

// ------------- pre-kernel: u[t][g][b][r] (f16) = U_h . x + b_h -------------
__global__ void __launch_bounds__(256) pre_kernel(
    const float* __restrict__ x_pred, const float* __restrict__ b_h,
    const float* __restrict__ U_h, f16* __restrict__ ubuf)
{
    const int tid = threadIdx.x;
    const int w = tid >> 6, l = tid & 63, lg = l >> 4, ln = l & 15;
    const int g = blockIdx.x & 7, tc = blockIdx.x >> 3;   // 4 timesteps per block
    const int b0 = g * GB;

    half8 uf[8][2];
    float4 bh4[8];
    #pragma unroll
    for (int j = 0; j < 8; ++j) {
        const int rt = 128 * w + 16 * j;
        bh4[j] = *(const float4*)(b_h + rt + 4 * lg);
        #pragma unroll
        for (int ks = 0; ks < 2; ++ks) {
            const float* p = U_h + (size_t)(rt + ln) * I_ + 32 * ks + 8 * lg;
            uf[j][ks] = cvt_h8(*(const float4*)p, *(const float4*)(p + 4));
        }
    }
    for (int tt = 0; tt < 4; ++tt) {
        const int t = tc * 4 + tt;
        half8 xf[2];
        #pragma unroll
        for (int ks = 0; ks < 2; ++ks) {
            const float* p = x_pred + ((size_t)(b0 + ln) * T_ + t) * I_ + 32 * ks + 8 * lg;
            xf[ks] = cvt_h8(*(const float4*)p, *(const float4*)(p + 4));
        }
        char* ut = (char*)ubuf + (size_t)(t * NG + g) * 16384;
        #pragma unroll
        for (int j = 0; j < 8; ++j) {
            f32x4 acc = {0.f, 0.f, 0.f, 0.f};
            acc = MFMA16(uf[j][0], xf[0], acc, 0, 0, 0);
            acc = MFMA16(uf[j][1], xf[1], acc, 0, 0, 0);
            const int rt = 128 * w + 16 * j;
            uint2 pk;
            pk.x = pack2(acc[0] + bh4[j].x, acc[1] + bh4[j].y);
            pk.y = pack2(acc[2] + bh4[j].z, acc[3] + bh4[j].w);
            *(uint2*)(ut + ln * 1024 + 2 * (rt + 4 * lg)) = pk;   // [b][r]
        }
    }
}

// ---- RNN kernel: 4 blocks x 16 waves, 2 groups/block, W fully in regs ----
__global__ void __launch_bounds__(1024, 4) rnn_kernel(
    const float* __restrict__ h0, const float* __restrict__ W_h,
    f16* __restrict__ uh, float* __restrict__ out)
{
    extern __shared__ char smem[];
    const int tid = threadIdx.x;
    const int w = tid >> 6, l = tid & 63, lg = l >> 4, ln = l & 15;
    const int q = w >> 3, wq = w & 7;          // group-within-block, wave-within-group
    const int g = blockIdx.x * 2 + q;          // global group id
    const int b0 = g * GB;
    const int rw = wq * 64;                    // wave's first output row
    char* hq = smem + q * GSTRIDE;             // this group's h double-buffer

    // ---- stage W rows [rw, rw+64) entirely into registers: fi = ks*4+j ----
    half8 wfr[64];
    #pragma unroll
    for (int ks = 0; ks < 16; ++ks) {
        #pragma unroll
        for (int j = 0; j < 4; ++j) {
            const float* p = W_h + (size_t)(rw + 16 * j + ln) * R_ + 32 * ks + 8 * lg;
            wfr[ks * 4 + j] = cvt_h8(*(const float4*)p, *(const float4*)(p + 4));
        }
    }
    // ---- stage h0 for both groups into buffer 0 (f16, XOR-swizzled [b][r]) ----
    {
        const int ba = tid >> 5, r0 = (tid & 31) * 16;   // ba: batch across 2 groups
        const int qq = ba >> 4, bq = ba & 15;
        const int sb = (bq & 7) << 4;
        const float* hp = h0 + (size_t)(blockIdx.x * 32 + ba) * R_ + r0;
        char* dst = smem + qq * GSTRIDE + bq * 1024;
        #pragma unroll
        for (int p = 0; p < 4; ++p) {
            float4 v = *(const float4*)(hp + 4 * p);
            uint2 pk;
            pk.x = pack2(v.x, v.y); pk.y = pack2(v.z, v.w);
            *(uint2*)(dst + ((2 * (r0 + 4 * p)) ^ sb)) = pk;
        }
    }
    // ---- prefetch u[0] ----
    uint2 uu[4];
    #pragma unroll
    for (int j = 0; j < 4; ++j)
        uu[j] = *(const uint2*)((char*)uh + (size_t)g * 16384 + ln * 1024 + 2 * (rw + 16 * j + 4 * lg));
    __syncthreads();   // one-time full barrier after staging

    const int asb = (ln & 7) << 4;   // swizzle mask (b = ln)

    #pragma unroll 1
    for (int t = 0; t < T_; ++t) {
        const char* hbp = hq + (t & 1) * HBYTES + ln * 1024;
        char* hn = hq + ((t & 1) ^ 1) * HBYTES;
        char* slot = (char*)uh + (size_t)(t * NG + g) * 16384;   // u[t] in, h[t+1] out ([b][r])
        const bool lastt = (t == T_ - 1);

        // acc <- u[t]  (rows rw+16j+4lg..+3, batch ln — matches D layout)
        f32x4 acc[4];
        #pragma unroll
        for (int j = 0; j < 4; ++j) {
            union { uint2 u; f16 h[4]; } c; c.u = uu[j];
            acc[j] = (f32x4){(float)c.h[0], (float)c.h[1], (float)c.h[2], (float)c.h[3]};
        }
        // prefetch u[t+1] (latency hidden under the MFMA loop)
        if (!lastt) {
            const char* un = (const char*)uh + (size_t)((t + 1) * NG + g) * 16384;
            #pragma unroll
            for (int j = 0; j < 4; ++j)
                uu[j] = *(const uint2*)(un + ln * 1024 + 2 * (rw + 16 * j + 4 * lg));
        }
        // ---- W.h over k=512: 16 ks; B-frag h from LDS; A-frags all registers ----
        #pragma unroll
        for (int ks = 0; ks < 16; ++ks) {
            half8 hb = *(const half8*)(hbp + ((64 * ks + 16 * lg) ^ asb));
            #pragma unroll
            for (int j = 0; j < 4; ++j)
                acc[j] = MFMA16(wfr[ks * 4 + j], hb, acc[j], 0, 0, 0);
        }
        // ---- finalize: tanh, publish h (global slot + LDS next buffer) ----
        #pragma unroll
        for (int j = 0; j < 4; ++j) {
            const int rb = 2 * (rw + 16 * j + 4 * lg);
            float v0 = tanh_fast(acc[j][0]), v1 = tanh_fast(acc[j][1]);
            float v2 = tanh_fast(acc[j][2]), v3 = tanh_fast(acc[j][3]);
            uint2 pk;
            pk.x = pack2(v0, v1); pk.y = pack2(v2, v3);
            *(uint2*)(slot + ln * 1024 + rb) = pk;               // h history, plain [b][r]
            if (!lastt) {
                *(uint2*)(hn + ln * 1024 + (rb ^ asb)) = pk;     // LDS next buffer (swizzled)
            } else {
                float* xd = out + (size_t)B_ * T_ * O_ + (size_t)(b0 + ln) * R_ + (rw + 16 * j + 4 * lg);
                float4 xv = make_float4(v0, v1, v2, v3);
                *(float4*)xd = xv;
                *(float4*)(xd + (size_t)B_ * R_) = xv;
            }
        }
        // Raw barrier: publish LDS h only (lgkmcnt). Global h-history stores and
        // u-prefetch stay in flight -- no vmcnt(0) drain on the per-step path.
        asm volatile("s_waitcnt lgkmcnt(0)\n\ts_barrier" ::: "memory");
    }
}

// ---------------- post-kernel: y[b][t][o] = W_out . h + b_out ----------------
__global__ void __launch_bounds__(256) y_kernel(
    const f16* __restrict__ hbuf, const float* __restrict__ W_out,
    const float* __restrict__ b_out, float* __restrict__ out)
{
    const int tid = threadIdx.x;
    const int w = tid >> 6, l = tid & 63, lg = l >> 4, ln = l & 15;
    const int g = blockIdx.x & 7, tc = blockIdx.x >> 3;
    const int b0 = g * GB;

    half8 wf[16];
    #pragma unroll
    for (int ks = 0; ks < 16; ++ks) {
        const float* p = W_out + (size_t)(16 * w + ln) * R_ + 32 * ks + 8 * lg;
        wf[ks] = cvt_h8(*(const float4*)p, *(const float4*)(p + 4));
    }
    const float bo = b_out[16 * w + ln];

    for (int tt = 0; tt < 4; ++tt) {
        const int t = tc * 4 + tt;
        const char* hb = (const char*)hbuf + (size_t)(t * NG + g) * 16384;   // [b][r]
        f32x4 acc = {0.f, 0.f, 0.f, 0.f};
        #pragma unroll
        for (int ks = 0; ks < 16; ++ks) {
            half8 a = *(const half8*)(hb + ln * 1024 + 64 * ks + 16 * lg);
            acc = MFMA16(a, wf[ks], acc, 0, 0, 0);
        }
        #pragma unroll
        for (int q = 0; q < 4; ++q) {
            const int b = 4 * lg + q;
            out[((size_t)(b0 + b) * T_ + t) * O_ + 16 * w + ln] = acc[q] + bo;
        }
    }
}

extern "C" void kernel_launch(void* const* d_in, const int* in_sizes, int n_in,
                              void* d_out, int out_size, void* d_ws, size_t ws_size,
                              hipStream_t stream) {
    const float* x_pred = (const float*)d_in[0];
    const float* h0     = (const float*)d_in[1];
    const float* W_h    = (const float*)d_in[2];
    const float* b_h    = (const float*)d_in[3];
    const float* U_h    = (const float*)d_in[4];
    const float* W_out  = (const float*)d_in[5];
    const float* b_out  = (const float*)d_in[6];
    float* out = (float*)d_out;

    f16* ubuf = (f16*)d_ws;   // u[t][g][b][r] f16, overwritten in-place by h[t+1]

    hipFuncSetAttribute(reinterpret_cast<const void*>(rnn_kernel),
                        hipFuncAttributeMaxDynamicSharedMemorySize, SMEM_TOTAL);

    pre_kernel<<<dim3(NG * 128), dim3(256), 0, stream>>>(x_pred, b_h, U_h, ubuf);
    rnn_kernel<<<dim3(4), dim3(1024), SMEM_TOTAL, stream>>>(h0, W_h, ubuf, out);
    y_kernel<<<dim3(NG * 128), dim3(256), 0, stream>>>(ubuf, W_out, b_out, out);
}

// Round 5
// 2056.154 us; speedup vs baseline: 6.5955x; 6.5955x over previous
//
#include <hip/hip_runtime.h>

#define B_ 128
#define T_ 512
#define I_ 64
#define R_ 512
#define O_ 64
#define NG 8          // batch groups (16 batches each); 1 block per group
#define GB 16

typedef _Float16 f16;
typedef __attribute__((ext_vector_type(8))) _Float16 half8;
typedef __attribute__((ext_vector_type(4))) float f32x4;

#define MFMA16 __builtin_amdgcn_mfma_f32_16x16x32_f16

// RNN block: 512 threads = 8 waves (2 waves/SIMD -> 256 arch regs/wave), wave w
// owns rows [64w, 64w+64). Per wave: 48 W frags in regs (j=0..2), 16 in LDS
// (j==3). The h B-operand (16 frags) is burst-prefetched into an 8-deep rolling
// register window right after the barrier, so the MFMA stream is not gated by
// per-iteration LDS latency (round-2's binding constraint: nothing saturated,
// step was read-latency-chained at 2 waves/SIMD).
// LDS: W 8x16KB = 128KB + h double-buffer 32KB = 163840 B (exact max).
#define NLW 16
#define WLDS_BYTES (8 * NLW * 1024)            // 131072
#define HOFF WLDS_BYTES
#define HBYTES 16384
#define SMEM_TOTAL (HOFF + 2 * HBYTES)         // 163840 == 160 KiB max

__device__ __forceinline__ float tanh_fast(float x) {
    float e = __expf(2.0f * x);
    return 1.0f - 2.0f * __builtin_amdgcn_rcpf(e + 1.0f);
}

__device__ __forceinline__ half8 cvt_h8(const float4 a, const float4 b) {
    half8 r;
    r[0] = (f16)a.x; r[1] = (f16)a.y; r[2] = (f16)a.z; r[3] = (f16)a.w;
    r[4] = (f16)b.x; r[5] = (f16)b.y; r[6] = (f16)b.z; r[7] = (f16)b.w;
    return r;
}

__device__ __forceinline__ unsigned pack2(float a, float b) {
    union { f16 h[2]; unsigned u; } r;
    r.h[0] = (f16)a; r.h[1] = (f16)b; return r.u;
}

// ------------- pre-kernel: u[t][g][b][r] (f16) = U_h . x + b_h -------------
__global__ void __launch_bounds__(256) pre_kernel(
    const float* __restrict__ x_pred, const float* __restrict__ b_h,
    const float* __restrict__ U_h, f16* __restrict__ ubuf)
{
    const int tid = threadIdx.x;
    const int w = tid >> 6, l = tid & 63, lg = l >> 4, ln = l & 15;
    const int g = blockIdx.x & 7, tc = blockIdx.x >> 3;   // 4 timesteps per block
    const int b0 = g * GB;

    half8 uf[8][2];
    float4 bh4[8];
    #pragma unroll
    for (int j = 0; j < 8; ++j) {
        const int rt = 128 * w + 16 * j;
        bh4[j] = *(const float4*)(b_h + rt + 4 * lg);
        #pragma unroll
        for (int ks = 0; ks < 2; ++ks) {
            const float* p = U_h + (size_t)(rt + ln) * I_ + 32 * ks + 8 * lg;
            uf[j][ks] = cvt_h8(*(const float4*)p, *(const float4*)(p + 4));
        }
    }
    for (int tt = 0; tt < 4; ++tt) {
        const int t = tc * 4 + tt;
        half8 xf[2];
        #pragma unroll
        for (int ks = 0; ks < 2; ++ks) {
            const float* p = x_pred + ((size_t)(b0 + ln) * T_ + t) * I_ + 32 * ks + 8 * lg;
            xf[ks] = cvt_h8(*(const float4*)p, *(const float4*)(p + 4));
        }
        char* ut = (char*)ubuf + (size_t)(t * NG + g) * 16384;
        #pragma unroll
        for (int j = 0; j < 8; ++j) {
            f32x4 acc = {0.f, 0.f, 0.f, 0.f};
            acc = MFMA16(uf[j][0], xf[0], acc, 0, 0, 0);
            acc = MFMA16(uf[j][1], xf[1], acc, 0, 0, 0);
            const int rt = 128 * w + 16 * j;
            uint2 pk;
            pk.x = pack2(acc[0] + bh4[j].x, acc[1] + bh4[j].y);
            pk.y = pack2(acc[2] + bh4[j].z, acc[3] + bh4[j].w);
            *(uint2*)(ut + ln * 1024 + 2 * (rt + 4 * lg)) = pk;   // [b][r]
        }
    }
}

// ---- RNN kernel: 1 block per group, 8 waves, B-burst + rolling register window ----
__global__ void __launch_bounds__(512, 2) rnn_kernel(
    const float* __restrict__ h0, const float* __restrict__ W_h,
    f16* __restrict__ uh, float* __restrict__ out)
{
    extern __shared__ char smem[];
    const int tid = threadIdx.x;
    const int w = tid >> 6, l = tid & 63, lg = l >> 4, ln = l & 15;
    const int g = blockIdx.x;
    const int b0 = g * GB;
    const int rw = w * 64;                     // wave's first output row
    char* wlds = smem + ((w * NLW) << 10) + (l << 4);   // this wave's LDS W frags

    // ---- stage W rows [rw, rw+64): j<3 -> regs (ridx=ks*3+j), j==3 -> LDS ----
    half8 wfr[48];
    #pragma unroll
    for (int ks = 0; ks < 16; ++ks) {
        #pragma unroll
        for (int j = 0; j < 4; ++j) {
            const float* p = W_h + (size_t)(rw + 16 * j + ln) * R_ + 32 * ks + 8 * lg;
            half8 f = cvt_h8(*(const float4*)p, *(const float4*)(p + 4));
            if (j == 3) *(half8*)(wlds + (ks << 10)) = f;
            else wfr[ks * 3 + j] = f;
        }
    }
    // ---- stage h0 into buffer 0 (f16, XOR-swizzled [b][r]); 512 threads ----
    {
        const int b = tid >> 5, r0 = (tid & 31) * 16;
        const int sb = (b & 7) << 4;
        const float* hp = h0 + (size_t)(b0 + b) * R_ + r0;
        #pragma unroll
        for (int q = 0; q < 4; ++q) {
            float4 v = *(const float4*)(hp + 4 * q);
            uint2 pk;
            pk.x = pack2(v.x, v.y); pk.y = pack2(v.z, v.w);
            *(uint2*)(smem + HOFF + b * 1024 + ((2 * (r0 + 4 * q)) ^ sb)) = pk;
        }
    }
    // ---- prefetch u[0] ----
    uint2 uu[4];
    #pragma unroll
    for (int j = 0; j < 4; ++j)
        uu[j] = *(const uint2*)((char*)uh + (size_t)g * 16384 + ln * 1024 + 2 * (rw + 16 * j + 4 * lg));
    __syncthreads();   // one-time full barrier after staging

    const int asb = (ln & 7) << 4;   // swizzle mask (b = ln)
    // B-read address, XOR pre-resolved into two bases so every ds_read is
    // base + compile-time immediate:
    //   offset(ks) = (64ks + 16lg) ^ asb
    //             = [bits4-5: 16lg ^ ((ln&3)<<4)] | [bit6: (ks&1)^ln2] | [128*(ks>>1)]
    const unsigned lanebase = (unsigned)(ln * 1024)
                            + (((unsigned)(16 * lg)) ^ ((unsigned)(ln & 3) << 4))
                            + (((unsigned)(ln >> 2) & 1u) << 6);

    #pragma unroll 1
    for (int t = 0; t < T_; ++t) {
        char* hc = smem + HOFF + (t & 1) * HBYTES;
        char* hn = smem + HOFF + ((t & 1) ^ 1) * HBYTES;
        const char* hbE = hc + lanebase;                  // ks even: +128*(ks>>1)
        const char* hbO = hc + (lanebase ^ 64u);          // ks odd:  +128*(ks>>1)
        char* slot = (char*)uh + (size_t)(t * NG + g) * 16384;   // u[t] in, h[t+1] out
        const bool lastt = (t == T_ - 1);

        #define BREAD(ks_) (*(const half8*)((((ks_) & 1) ? hbO : hbE) + 128 * ((ks_) >> 1)))

        // ---- burst-issue B-frags ks 0..7 into the rolling window ----
        half8 bb[8];
        #pragma unroll
        for (int k = 0; k < 8; ++k) bb[k] = BREAD(k);

        // acc <- u[t]
        f32x4 acc[4];
        #pragma unroll
        for (int j = 0; j < 4; ++j) {
            union { uint2 u; f16 h[4]; } c; c.u = uu[j];
            acc[j] = (f32x4){(float)c.h[0], (float)c.h[1], (float)c.h[2], (float)c.h[3]};
        }
        // prefetch u[t+1] (global; hidden under MFMA loop)
        if (!lastt) {
            const char* un = (const char*)uh + (size_t)((t + 1) * NG + g) * 16384;
            #pragma unroll
            for (int j = 0; j < 4; ++j)
                uu[j] = *(const uint2*)(un + ln * 1024 + 2 * (rw + 16 * j + 4 * lg));
        }
        // ---- K-loop: B from registers (rolling reload), A regs + 1 LDS frag ----
        #pragma unroll
        for (int ks = 0; ks < 16; ++ks) {
            const int bi = ks & 7;                       // compile-time (unrolled)
            half8 hb = bb[bi];
            half8 a3 = *(const half8*)(wlds + (ks << 10));
            acc[0] = MFMA16(wfr[ks * 3 + 0], hb, acc[0], 0, 0, 0);
            acc[1] = MFMA16(wfr[ks * 3 + 1], hb, acc[1], 0, 0, 0);
            acc[2] = MFMA16(wfr[ks * 3 + 2], hb, acc[2], 0, 0, 0);
            acc[3] = MFMA16(a3, hb, acc[3], 0, 0, 0);
            if (ks < 8) bb[bi] = BREAD(ks + 8);          // reload for second half
        }
        #undef BREAD

        // ---- finalize: tanh, publish h (global slot + LDS next buffer) ----
        #pragma unroll
        for (int j = 0; j < 4; ++j) {
            const int rb = 2 * (rw + 16 * j + 4 * lg);
            float v0 = tanh_fast(acc[j][0]), v1 = tanh_fast(acc[j][1]);
            float v2 = tanh_fast(acc[j][2]), v3 = tanh_fast(acc[j][3]);
            uint2 pk;
            pk.x = pack2(v0, v1); pk.y = pack2(v2, v3);
            *(uint2*)(slot + ln * 1024 + rb) = pk;               // h history [b][r]
            if (!lastt) {
                *(uint2*)(hn + ln * 1024 + (rb ^ asb)) = pk;     // LDS next buffer
            } else {
                float* xd = out + (size_t)B_ * T_ * O_ + (size_t)(b0 + ln) * R_ + (rw + 16 * j + 4 * lg);
                float4 xv = make_float4(v0, v1, v2, v3);
                *(float4*)xd = xv;
                *(float4*)(xd + (size_t)B_ * R_) = xv;
            }
        }
        // Raw barrier: publish LDS h only (lgkmcnt). Global stores + u-prefetch
        // stay in flight -- no vmcnt(0) drain on the per-step path.
        asm volatile("s_waitcnt lgkmcnt(0)\n\ts_barrier" ::: "memory");
    }
}

// ---------------- post-kernel: y[b][t][o] = W_out . h + b_out ----------------
__global__ void __launch_bounds__(256) y_kernel(
    const f16* __restrict__ hbuf, const float* __restrict__ W_out,
    const float* __restrict__ b_out, float* __restrict__ out)
{
    const int tid = threadIdx.x;
    const int w = tid >> 6, l = tid & 63, lg = l >> 4, ln = l & 15;
    const int g = blockIdx.x & 7, tc = blockIdx.x >> 3;
    const int b0 = g * GB;

    half8 wf[16];
    #pragma unroll
    for (int ks = 0; ks < 16; ++ks) {
        const float* p = W_out + (size_t)(16 * w + ln) * R_ + 32 * ks + 8 * lg;
        wf[ks] = cvt_h8(*(const float4*)p, *(const float4*)(p + 4));
    }
    const float bo = b_out[16 * w + ln];

    for (int tt = 0; tt < 4; ++tt) {
        const int t = tc * 4 + tt;
        const char* hb = (const char*)hbuf + (size_t)(t * NG + g) * 16384;   // [b][r]
        f32x4 acc = {0.f, 0.f, 0.f, 0.f};
        #pragma unroll
        for (int ks = 0; ks < 16; ++ks) {
            half8 a = *(const half8*)(hb + ln * 1024 + 64 * ks + 16 * lg);
            acc = MFMA16(a, wf[ks], acc, 0, 0, 0);
        }
        #pragma unroll
        for (int q = 0; q < 4; ++q) {
            const int b = 4 * lg + q;
            out[((size_t)(b0 + b) * T_ + t) * O_ + 16 * w + ln] = acc[q] + bo;
        }
    }
}

extern "C" void kernel_launch(void* const* d_in, const int* in_sizes, int n_in,
                              void* d_out, int out_size, void* d_ws, size_t ws_size,
                              hipStream_t stream) {
    const float* x_pred = (const float*)d_in[0];
    const float* h0     = (const float*)d_in[1];
    const float* W_h    = (const float*)d_in[2];
    const float* b_h    = (const float*)d_in[3];
    const float* U_h    = (const float*)d_in[4];
    const float* W_out  = (const float*)d_in[5];
    const float* b_out  = (const float*)d_in[6];
    float* out = (float*)d_out;

    f16* ubuf = (f16*)d_ws;   // u[t][g][b][r] f16, overwritten in-place by h[t+1]

    hipFuncSetAttribute(reinterpret_cast<const void*>(rnn_kernel),
                        hipFuncAttributeMaxDynamicSharedMemorySize, SMEM_TOTAL);

    pre_kernel<<<dim3(NG * 128), dim3(256), 0, stream>>>(x_pred, b_h, U_h, ubuf);
    rnn_kernel<<<dim3(NG), dim3(512), SMEM_TOTAL, stream>>>(h0, W_h, ubuf, out);
    y_kernel<<<dim3(NG * 128), dim3(256), 0, stream>>>(ubuf, W_out, b_out, out);
}

// Round 9
// 1759.332 us; speedup vs baseline: 7.7083x; 1.1687x over previous
//
#include <hip/hip_runtime.h>

#define B_ 128
#define T_ 512
#define I_ 64
#define R_ 512
#define O_ 64
#define NG 8          // batch groups (16 batches each); 1 block per group
#define GB 16

typedef _Float16 f16;
typedef __attribute__((ext_vector_type(8))) _Float16 half8;
typedef __attribute__((ext_vector_type(2))) __fp16 fp16x2;
typedef __attribute__((ext_vector_type(4))) float f32x4;

#define MFMA16 __builtin_amdgcn_mfma_f32_16x16x32_f16

// RNN block: 512 threads = 8 waves (2 waves/SIMD), wave w owns rows
// [64w, 64w+64) = 4 m-tiles. Round-2 structure (proven best across rounds
// 1-7): JIT per-slice B-reads that the compiler software-pipelines, one raw
// lgkmcnt-only barrier per step. This round: micro-trims only --
// (1) XOR swizzle pre-resolved into 2 base pointers (B-reads = base+imm),
// (2) v_cvt_pkrtz packing, (3) s_setprio(1) around the MFMA slice loop.
#define NLW 15
#define NRW 49
#define WLDS_BYTES (8 * NLW * 1024)            // 122880
#define HOFF WLDS_BYTES
#define HBYTES 16384
#define SMEM_TOTAL (WLDS_BYTES + 2 * HBYTES)   // 155648 <= 163840

__device__ __forceinline__ float tanh_fast(float x) {
    float e = __expf(2.0f * x);
    return 1.0f - 2.0f * __builtin_amdgcn_rcpf(e + 1.0f);
}

__device__ __forceinline__ half8 cvt_h8(const float4 a, const float4 b) {
    half8 r;
    r[0] = (f16)a.x; r[1] = (f16)a.y; r[2] = (f16)a.z; r[3] = (f16)a.w;
    r[4] = (f16)b.x; r[5] = (f16)b.y; r[6] = (f16)b.z; r[7] = (f16)b.w;
    return r;
}

__device__ __forceinline__ unsigned pack2(float a, float b) {
    // single v_cvt_pkrtz_f16_f32 (RTZ; delta << f16 threshold)
    union { fp16x2 h; unsigned u; } r;
    r.h = __builtin_amdgcn_cvt_pkrtz(a, b);
    return r.u;
}

// ------------- pre-kernel: u[t][g][b][r] (f16) = U_h . x + b_h -------------
__global__ void __launch_bounds__(256) pre_kernel(
    const float* __restrict__ x_pred, const float* __restrict__ b_h,
    const float* __restrict__ U_h, f16* __restrict__ ubuf)
{
    const int tid = threadIdx.x;
    const int w = tid >> 6, l = tid & 63, lg = l >> 4, ln = l & 15;
    const int g = blockIdx.x & 7, tc = blockIdx.x >> 3;   // 4 timesteps per block
    const int b0 = g * GB;

    half8 uf[8][2];
    float4 bh4[8];
    #pragma unroll
    for (int j = 0; j < 8; ++j) {
        const int rt = 128 * w + 16 * j;
        bh4[j] = *(const float4*)(b_h + rt + 4 * lg);
        #pragma unroll
        for (int ks = 0; ks < 2; ++ks) {
            const float* p = U_h + (size_t)(rt + ln) * I_ + 32 * ks + 8 * lg;
            uf[j][ks] = cvt_h8(*(const float4*)p, *(const float4*)(p + 4));
        }
    }
    for (int tt = 0; tt < 4; ++tt) {
        const int t = tc * 4 + tt;
        half8 xf[2];
        #pragma unroll
        for (int ks = 0; ks < 2; ++ks) {
            const float* p = x_pred + ((size_t)(b0 + ln) * T_ + t) * I_ + 32 * ks + 8 * lg;
            xf[ks] = cvt_h8(*(const float4*)p, *(const float4*)(p + 4));
        }
        char* ut = (char*)ubuf + (size_t)(t * NG + g) * 16384;
        #pragma unroll
        for (int j = 0; j < 8; ++j) {
            f32x4 acc = {0.f, 0.f, 0.f, 0.f};
            acc = MFMA16(uf[j][0], xf[0], acc, 0, 0, 0);
            acc = MFMA16(uf[j][1], xf[1], acc, 0, 0, 0);
            const int rt = 128 * w + 16 * j;
            uint2 pk;
            pk.x = pack2(acc[0] + bh4[j].x, acc[1] + bh4[j].y);
            pk.y = pack2(acc[2] + bh4[j].z, acc[3] + bh4[j].w);
            *(uint2*)(ut + ln * 1024 + 2 * (rt + 4 * lg)) = pk;   // [b][r]
        }
    }
}

// ---- RNN kernel: 1 block per group, 8 waves, round-2 structure + micro ----
__global__ void __launch_bounds__(512, 2) rnn_kernel(
    const float* __restrict__ h0, const float* __restrict__ W_h,
    f16* __restrict__ uh, float* __restrict__ out)
{
    extern __shared__ char smem[];
    const int tid = threadIdx.x;
    const int w = tid >> 6, l = tid & 63, lg = l >> 4, ln = l & 15;
    const int g = blockIdx.x;
    const int b0 = g * GB;
    const int rw = w * 64;                     // wave's first output row
    char* wlds = smem + ((w * NLW) << 10) + (l << 4);   // this wave's LDS W frags

    // ---- stage W rows [rw, rw+64) as A-frags: fi = ks*4+j; 15 LDS + 49 reg ----
    half8 wfr[NRW];
    #pragma unroll
    for (int j = 0; j < 4; ++j) {
        const float* wr = W_h + (size_t)(rw + 16 * j + ln) * R_;
        #pragma unroll
        for (int ks = 0; ks < 16; ++ks) {
            const float* p = wr + 32 * ks + 8 * lg;
            half8 f = cvt_h8(*(const float4*)p, *(const float4*)(p + 4));
            const int fi = ks * 4 + j;
            if (fi < NLW) *(half8*)(wlds + (fi << 10)) = f;
            else wfr[fi - NLW] = f;
        }
    }
    // ---- stage h0 into buffer 0 (f16, XOR-swizzled [b][r]); 512 threads ----
    {
        const int b = tid >> 5, r0 = (tid & 31) * 16;
        const int sb = (b & 7) << 4;
        const float* hp = h0 + (size_t)(b0 + b) * R_ + r0;
        #pragma unroll
        for (int q = 0; q < 4; ++q) {
            float4 v = *(const float4*)(hp + 4 * q);
            uint2 pk;
            pk.x = pack2(v.x, v.y); pk.y = pack2(v.z, v.w);
            *(uint2*)(smem + HOFF + b * 1024 + ((2 * (r0 + 4 * q)) ^ sb)) = pk;
        }
    }
    // ---- prefetch u[0] for this wave's rows (uint2 from [b][r] slab) ----
    uint2 uu[4];
    #pragma unroll
    for (int j = 0; j < 4; ++j)
        uu[j] = *(const uint2*)((char*)uh + (size_t)g * 16384 + ln * 1024 + 2 * (rw + 16 * j + 4 * lg));
    __syncthreads();   // one-time full barrier after staging

    const int asb = (ln & 7) << 4;   // swizzle mask (b = ln), for FIN writes
    // B-read XOR pre-resolved: offset(ks) = (64ks+16lg)^asb
    //  = [16lg ^ ((ln&3)<<4)] | [((ks&1)^((ln>>2)&1))<<6] | 128*(ks>>1)
    // -> two bases (even/odd ks), every ds_read is base + compile-time imm.
    const unsigned lanebase = (unsigned)(ln * 1024)
                            + (((unsigned)(16 * lg)) ^ ((unsigned)(ln & 3) << 4))
                            + (((unsigned)(ln >> 2) & 1u) << 6);

    #pragma unroll 1
    for (int t = 0; t < T_; ++t) {
        char* hc = smem + HOFF + (t & 1) * HBYTES;
        char* hn = smem + HOFF + ((t & 1) ^ 1) * HBYTES;
        const char* hbE = hc + lanebase;                  // even ks: +128*(ks>>1)
        const char* hbO = hc + (lanebase ^ 64u);          // odd  ks: +128*(ks>>1)
        char* slot = (char*)uh + (size_t)(t * NG + g) * 16384;   // u[t] in, h[t+1] out
        const bool lastt = (t == T_ - 1);

        // acc <- u[t]  (rows rw+16j+4lg..+3, batch ln — matches D layout)
        f32x4 acc[4];
        #pragma unroll
        for (int j = 0; j < 4; ++j) {
            union { uint2 u; f16 h[4]; } c; c.u = uu[j];
            acc[j] = (f32x4){(float)c.h[0], (float)c.h[1], (float)c.h[2], (float)c.h[3]};
        }
        // prefetch u[t+1] (latency hidden under MFMA loop; compiler's counted
        // vmcnt before next step's acc-init keeps h-stores un-drained)
        if (!lastt) {
            const char* un = (const char*)uh + (size_t)((t + 1) * NG + g) * 16384;
            #pragma unroll
            for (int j = 0; j < 4; ++j)
                uu[j] = *(const uint2*)(un + ln * 1024 + 2 * (rw + 16 * j + 4 * lg));
        }
        // ---- W.h over k=512: 16 ks; B-frag h JIT from LDS (base+imm);
        // A-frags regs + 1 LDS. setprio(1): the wave still streaming MFMAs
        // outranks its SIMD-mate already in the FIN VALU tail.
        __builtin_amdgcn_s_setprio(1);
        #pragma unroll
        for (int ks = 0; ks < 16; ++ks) {
            half8 hb = *(const half8*)((ks & 1 ? hbO : hbE) + 128 * (ks >> 1));
            #pragma unroll
            for (int j = 0; j < 4; ++j) {
                const int fi = ks * 4 + j;
                half8 aa;
                if (fi < NLW) aa = *(const half8*)(wlds + (fi << 10));
                else aa = wfr[fi - NLW];
                acc[j] = MFMA16(aa, hb, acc[j], 0, 0, 0);
            }
        }
        __builtin_amdgcn_s_setprio(0);
        // ---- finalize: tanh, publish h (global slot + LDS next buffer) ----
        #pragma unroll
        for (int j = 0; j < 4; ++j) {
            const int rb = 2 * (rw + 16 * j + 4 * lg);
            float v0 = tanh_fast(acc[j][0]), v1 = tanh_fast(acc[j][1]);
            float v2 = tanh_fast(acc[j][2]), v3 = tanh_fast(acc[j][3]);
            uint2 pk;
            pk.x = pack2(v0, v1); pk.y = pack2(v2, v3);
            *(uint2*)(slot + ln * 1024 + rb) = pk;               // h history [b][r]
            if (!lastt) {
                *(uint2*)(hn + ln * 1024 + (rb ^ asb)) = pk;     // LDS next buffer
            } else {
                float* xd = out + (size_t)B_ * T_ * O_ + (size_t)(b0 + ln) * R_ + (rw + 16 * j + 4 * lg);
                float4 xv = make_float4(v0, v1, v2, v3);
                *(float4*)xd = xv;
                *(float4*)(xd + (size_t)B_ * R_) = xv;
            }
        }
        // Raw barrier: publish LDS h only (lgkmcnt). Global h-history stores and
        // u-prefetch stay in flight -- no vmcnt(0) drain on the per-step path.
        asm volatile("s_waitcnt lgkmcnt(0)\n\ts_barrier" ::: "memory");
    }
}

// ---------------- post-kernel: y[b][t][o] = W_out . h + b_out ----------------
__global__ void __launch_bounds__(256) y_kernel(
    const f16* __restrict__ hbuf, const float* __restrict__ W_out,
    const float* __restrict__ b_out, float* __restrict__ out)
{
    const int tid = threadIdx.x;
    const int w = tid >> 6, l = tid & 63, lg = l >> 4, ln = l & 15;
    const int g = blockIdx.x & 7, tc = blockIdx.x >> 3;
    const int b0 = g * GB;

    half8 wf[16];
    #pragma unroll
    for (int ks = 0; ks < 16; ++ks) {
        const float* p = W_out + (size_t)(16 * w + ln) * R_ + 32 * ks + 8 * lg;
        wf[ks] = cvt_h8(*(const float4*)p, *(const float4*)(p + 4));
    }
    const float bo = b_out[16 * w + ln];

    for (int tt = 0; tt < 4; ++tt) {
        const int t = tc * 4 + tt;
        const char* hb = (const char*)hbuf + (size_t)(t * NG + g) * 16384;   // [b][r]
        f32x4 acc = {0.f, 0.f, 0.f, 0.f};
        #pragma unroll
        for (int ks = 0; ks < 16; ++ks) {
            half8 a = *(const half8*)(hb + ln * 1024 + 64 * ks + 16 * lg);
            acc = MFMA16(a, wf[ks], acc, 0, 0, 0);
        }
        #pragma unroll
        for (int q = 0; q < 4; ++q) {
            const int b = 4 * lg + q;
            out[((size_t)(b0 + b) * T_ + t) * O_ + 16 * w + ln] = acc[q] + bo;
        }
    }
}

extern "C" void kernel_launch(void* const* d_in, const int* in_sizes, int n_in,
                              void* d_out, int out_size, void* d_ws, size_t ws_size,
                              hipStream_t stream) {
    const float* x_pred = (const float*)d_in[0];
    const float* h0     = (const float*)d_in[1];
    const float* W_h    = (const float*)d_in[2];
    const float* b_h    = (const float*)d_in[3];
    const float* U_h    = (const float*)d_in[4];
    const float* W_out  = (const float*)d_in[5];
    const float* b_out  = (const float*)d_in[6];
    float* out = (float*)d_out;

    f16* ubuf = (f16*)d_ws;   // u[t][g][b][r] f16, overwritten in-place by h[t+1]

    (void)hipFuncSetAttribute(reinterpret_cast<const void*>(rnn_kernel),
                              hipFuncAttributeMaxDynamicSharedMemorySize, SMEM_TOTAL);

    pre_kernel<<<dim3(NG * 128), dim3(256), 0, stream>>>(x_pred, b_h, U_h, ubuf);
    rnn_kernel<<<dim3(NG), dim3(512), SMEM_TOTAL, stream>>>(h0, W_h, ubuf, out);
    y_kernel<<<dim3(NG * 128), dim3(256), 0, stream>>>(ubuf, W_out, b_out, out);
}